// Round 7
// baseline (148.061 us; speedup 1.0000x reference)
//
#include <hip/hip_runtime.h>
#include <hip/hip_cooperative_groups.h>
#include <math.h>

namespace cg = cooperative_groups;

#define DD 512
#define KC 32
#define NQ 524288
#define EPSF 1e-8f
#define CONE_STRIDE 13

typedef float f4 __attribute__((ext_vector_type(4)));

__device__ __constant__ float c_mult[8]  = {1.f, 1.f, 1.f, 0.01f, 0.03f, 1.7f, 1.7f, 1.7f};
__device__ __constant__ float c_adder[8] = {-0.8f, -0.8f, -0.8f, 0.05f, 0.1f, -1.f, -1.f, -1.f};

// ======================= fused middle (cooperative) =======================
// 256 blocks x 512 threads (2x co-residency headroom at launch_bounds(512,4)).
// ENC (all blocks, 128 rows each) -> sync -> DEC (128 blk) -> sync ->
// MAP (64 blk) -> sync -> PARAMS (block 0 only: 64KB L2-hot reduce + cones).
__global__ __launch_bounds__(512, 4) void k_mid(
        const float* __restrict__ vox,  const float* __restrict__ Wenc,
        const float* __restrict__ benc, const float* __restrict__ Wdec,
        const float* __restrict__ bdec, const float* __restrict__ Wmap,
        const float* __restrict__ bmap,
        float* __restrict__ partialT,   float* __restrict__ decPart,
        float* __restrict__ mapPart,    float* __restrict__ out_params,
        float* __restrict__ cones) {
    cg::grid_group grid = cg::this_grid();
    __shared__ float4 red4[512];
    __shared__ float wsum[8];
    __shared__ float dec8[8];
    __shared__ float half0[256];
    __shared__ float pbuf[256];
    const int t = threadIdx.x;
    const int b = blockIdx.x;

    // ---------- ENC: two 64-row chunks -> partialT[d][2b], [d][2b+1] ----------
    #pragma unroll
    for (int chunk = 0; chunk < 2; ++chunk) {
        const int bb = b * 2 + chunk;
        const int g  = t >> 7;
        const int c4 = (t & 127) << 2;
        const int v0 = bb * 64;
        float4 acc = make_float4(0.f, 0.f, 0.f, 0.f);
        #pragma unroll
        for (int it = 0; it < 16; ++it) {
            const int v = v0 + it * 4 + g;
            const float sv = vox[v];
            const float4 w = *reinterpret_cast<const float4*>(&Wenc[(size_t)v * DD + c4]);
            acc.x += sv * w.x; acc.y += sv * w.y; acc.z += sv * w.z; acc.w += sv * w.w;
        }
        __syncthreads();             // protect red4 reuse across chunks
        red4[t] = acc;
        __syncthreads();
        const float* red = reinterpret_cast<const float*>(red4);
        partialT[(size_t)t * 512 + bb] = red[t] + red[512 + t] + red[1024 + t] + red[1536 + t];
    }
    grid.sync();

    // ---------- DEC: decPart[b][d], blocks 0..127 (4 rows each) ----------
    if (b < 128) {
        const int g = t >> 7;
        const int j = t & 127;
        const int i = b * 4 + g;
        const float4 pv = *reinterpret_cast<const float4*>(&partialT[(size_t)i * 512 + j * 4]);
        float s = pv.x + pv.y + pv.z + pv.w;
        #pragma unroll
        for (int off = 32; off >= 1; off >>= 1) s += __shfl_xor(s, off, 64);
        if ((t & 63) == 0) wsum[t >> 6] = s;
        __syncthreads();
        float fi = wsum[2 * g] + wsum[2 * g + 1] + benc[i];
        fi = fi > 0.f ? fi : 0.f;
        const float4 w = *reinterpret_cast<const float4*>(&Wdec[(size_t)i * DD + (j << 2)]);
        red4[t] = make_float4(fi * w.x, fi * w.y, fi * w.z, fi * w.w);
        __syncthreads();
        const float* red = reinterpret_cast<const float*>(red4);
        decPart[(size_t)b * 512 + t] = red[t] + red[512 + t] + red[1024 + t] + red[1536 + t];
    }
    grid.sync();

    // ---------- MAP: mapPart[b][j], blocks 0..63 (8 rows each) ----------
    if (b < 64) {
        const int w = t >> 6, l = t & 63;
        const int i = b * 8 + w;
        float s = decPart[(size_t)(2 * l) * 512 + i] + decPart[(size_t)(2 * l + 1) * 512 + i];
        #pragma unroll
        for (int off = 32; off >= 1; off >>= 1) s += __shfl_xor(s, off, 64);
        if (l == 0) {
            const float d = s + bdec[i];
            dec8[w] = d > 0.f ? d : 0.f;
        }
        __syncthreads();
        const int j = t & 255, h = t >> 8;
        float acc = 0.f;
        #pragma unroll
        for (int r = 0; r < 4; ++r) {
            const int row = h * 4 + r;
            acc += dec8[row] * Wmap[(size_t)(b * 8 + row) * 256 + j];
        }
        if (h == 0) half0[j] = acc;
        __syncthreads();
        if (h == 1) mapPart[(size_t)b * 256 + j] = half0[j] + acc;
    }
    grid.sync();

    // ---------- PARAMS: block 0 only ----------
    if (b == 0) {
        const int j = t & 255, h = t >> 8;
        float m = 0.f;
        #pragma unroll 8
        for (int pi = h * 32; pi < h * 32 + 32; ++pi) m += mapPart[(size_t)pi * 256 + j];
        if (h == 0) half0[j] = m;
        __syncthreads();
        if (h == 1) {
            const float tot = half0[j] + m + bmap[j];
            const float sig = 1.f / (1.f + expf(-tot));
            const float val = sig * c_mult[j & 7] + c_adder[j & 7];
            pbuf[j] = val;
            out_params[j] = val;
        }
        __syncthreads();
        if (t < KC) {
            const float cx = pbuf[t*8+0], cy = pbuf[t*8+1], cz = pbuf[t*8+2];
            const float r  = pbuf[t*8+3], hh = pbuf[t*8+4];
            const float ox = pbuf[t*8+5], oy = pbuf[t*8+6], oz = pbuf[t*8+7];
            const float nrm = sqrtf(ox*ox + oy*oy + oz*oz) + EPSF;
            const float inv = 1.f / nrm;
            const float inv_h = 1.f / (hh + EPSF);
            float* ck = &cones[t * CONE_STRIDE];
            ck[0] = cx;        ck[1] = cy;       ck[2] = cz;
            ck[3] = ox * inv;  ck[4] = oy * inv; ck[5] = oz * inv;
            ck[6] = r;         ck[7] = hh;       ck[8] = inv_h;
            ck[9] = r * inv_h; ck[10] = 0.f;     ck[11] = 0.f;  ck[12] = 0.f;
        }
    }
}

// ======================= R5 fallback kernels (proven) =======================
__global__ __launch_bounds__(512) void k_enc(const float* __restrict__ vox,
                                             const float* __restrict__ Wenc,
                                             float* __restrict__ partialT) {
    __shared__ float4 red4[512];
    const int t = threadIdx.x;
    const int b = blockIdx.x;
    const int g  = t >> 7;
    const int c4 = (t & 127) << 2;
    const int v0 = b * 64;
    float4 acc = make_float4(0.f, 0.f, 0.f, 0.f);
    #pragma unroll
    for (int it = 0; it < 16; ++it) {
        const int v = v0 + it * 4 + g;
        const float sv = vox[v];
        const float4 w = *reinterpret_cast<const float4*>(&Wenc[(size_t)v * DD + c4]);
        acc.x += sv * w.x; acc.y += sv * w.y; acc.z += sv * w.z; acc.w += sv * w.w;
    }
    red4[t] = acc;
    __syncthreads();
    const float* red = reinterpret_cast<const float*>(red4);
    partialT[(size_t)t * 512 + b] = red[t] + red[512 + t] + red[1024 + t] + red[1536 + t];
}

__global__ __launch_bounds__(512) void k_dec(const float* __restrict__ partialT,
                                             const float* __restrict__ benc,
                                             const float* __restrict__ Wdec,
                                             float* __restrict__ decPart) {
    __shared__ float4 red4[512];
    __shared__ float wsum[8];
    const int t = threadIdx.x;
    const int g = t >> 7;
    const int j = t & 127;
    const int i = blockIdx.x * 4 + g;
    const float4 pv = *reinterpret_cast<const float4*>(&partialT[(size_t)i * 512 + j * 4]);
    float s = pv.x + pv.y + pv.z + pv.w;
    #pragma unroll
    for (int off = 32; off >= 1; off >>= 1) s += __shfl_xor(s, off, 64);
    if ((t & 63) == 0) wsum[t >> 6] = s;
    __syncthreads();
    float fi = wsum[2 * g] + wsum[2 * g + 1] + benc[i];
    fi = fi > 0.f ? fi : 0.f;
    const float4 w = *reinterpret_cast<const float4*>(&Wdec[(size_t)i * DD + (j << 2)]);
    red4[t] = make_float4(fi * w.x, fi * w.y, fi * w.z, fi * w.w);
    __syncthreads();
    const float* red = reinterpret_cast<const float*>(red4);
    decPart[(size_t)blockIdx.x * 512 + t] = red[t] + red[512 + t] + red[1024 + t] + red[1536 + t];
}

__global__ __launch_bounds__(512) void k_map(const float* __restrict__ decPart,
                                             const float* __restrict__ bdec,
                                             const float* __restrict__ Wmap,
                                             float* __restrict__ mapPart) {
    __shared__ float dec8[8];
    __shared__ float half0[256];
    const int t = threadIdx.x;
    const int b = blockIdx.x;
    const int w = t >> 6, l = t & 63;
    const int i = b * 8 + w;
    float s = decPart[(size_t)(2 * l) * 512 + i] + decPart[(size_t)(2 * l + 1) * 512 + i];
    #pragma unroll
    for (int off = 32; off >= 1; off >>= 1) s += __shfl_xor(s, off, 64);
    if (l == 0) {
        const float d = s + bdec[i];
        dec8[w] = d > 0.f ? d : 0.f;
    }
    __syncthreads();
    const int j = t & 255, h = t >> 8;
    float acc = 0.f;
    #pragma unroll
    for (int r = 0; r < 4; ++r) {
        const int row = h * 4 + r;
        acc += dec8[row] * Wmap[(size_t)(b * 8 + row) * 256 + j];
    }
    if (h == 0) half0[j] = acc;
    __syncthreads();
    if (h == 1) mapPart[(size_t)b * 256 + j] = half0[j] + acc;
}

__global__ __launch_bounds__(256) void k_params(const float* __restrict__ mapPart,
                                                const float* __restrict__ bmap,
                                                float* __restrict__ out_params,
                                                float* __restrict__ cones) {
    __shared__ float p[256];
    const int j = threadIdx.x;
    float m = 0.f;
    #pragma unroll 8
    for (int pi = 0; pi < 64; ++pi) m += mapPart[(size_t)pi * 256 + j];
    const float tot = m + bmap[j];
    const float sig = 1.f / (1.f + expf(-tot));
    const float val = sig * c_mult[j & 7] + c_adder[j & 7];
    out_params[j] = val;
    p[j] = val;
    __syncthreads();
    if (j < KC) {
        const float cx = p[j*8+0], cy = p[j*8+1], cz = p[j*8+2];
        const float r  = p[j*8+3], hh = p[j*8+4];
        const float ox = p[j*8+5], oy = p[j*8+6], oz = p[j*8+7];
        const float nrm = sqrtf(ox*ox + oy*oy + oz*oz) + EPSF;
        const float inv = 1.f / nrm;
        const float inv_h = 1.f / (hh + EPSF);
        float* ck = &cones[j * CONE_STRIDE];
        ck[0] = cx;        ck[1] = cy;       ck[2] = cz;
        ck[3] = ox * inv;  ck[4] = oy * inv; ck[5] = oz * inv;
        ck[6] = r;         ck[7] = hh;       ck[8] = inv_h;
        ck[9] = r * inv_h; ck[10] = 0.f;     ck[11] = 0.f;  ck[12] = 0.f;
    }
}

// ======================= SDF (always separate, full occupancy) ==============
__global__ __launch_bounds__(256) void k_sdf(const float* __restrict__ q,
                                             const float* __restrict__ cones,
                                             float* __restrict__ out) {
    __shared__ float c[KC * CONE_STRIDE];
    const int t = threadIdx.x;
    c[t] = cones[t];
    if (t < KC * CONE_STRIDE - 256) c[256 + t] = cones[256 + t];
    __syncthreads();
    const int k0 = (t & 7) << 2;
    float cx[4], cy[4], cz[4], ax[4], ay[4], az[4], cr[4], chh[4], rih[4];
    #pragma unroll
    for (int kk = 0; kk < 4; ++kk) {
        const float* ck = &c[(k0 + kk) * CONE_STRIDE];
        cx[kk] = ck[0]; cy[kk] = ck[1]; cz[kk] = ck[2];
        ax[kk] = ck[3]; ay[kk] = ck[4]; az[kk] = ck[5];
        cr[kk] = ck[6]; chh[kk] = ck[7]; rih[kk] = ck[9];
    }
    const size_t qbase = (size_t)blockIdx.x * 256;
    const int nl = t >> 3;
    #pragma unroll
    for (int tile = 0; tile < 8; ++tile) {
        const size_t n = qbase + tile * 32 + nl;
        const float qx = q[n * 3 + 0];
        const float qy = q[n * 3 + 1];
        const float qz = q[n * 3 + 2];
        f4 o;
        #pragma unroll
        for (int kk = 0; kk < 4; ++kk) {
            const float vx = qx - cx[kk];
            const float vy = qy - cy[kk];
            const float vz = qz - cz[kk];
            const float proj = vx*ax[kk] + vy*ay[kk] + vz*az[kk];
            const float d2 = vx*vx + vy*vy + vz*vz;
            float pp = d2 - proj * proj;
            pp = pp > 0.f ? pp : 0.f;
            const float perp = sqrtf(pp);
            const float slant = perp - cr[kk] + rih[kk] * proj;
            const float cap = fabsf(proj) - chh[kk];
            o[kk] = slant > cap ? slant : cap;
        }
        __builtin_nontemporal_store(o, reinterpret_cast<f4*>(&out[n * (size_t)KC + k0]));
    }
}

extern "C" void kernel_launch(void* const* d_in, const int* in_sizes, int n_in,
                              void* d_out, int out_size, void* d_ws, size_t ws_size,
                              hipStream_t stream) {
    const float* vox  = (const float*)d_in[0];
    const float* q    = (const float*)d_in[1];
    // d_in[2] = initial_centers: unused by the reference
    const float* Wenc = (const float*)d_in[3];
    const float* benc = (const float*)d_in[4];
    const float* Wdec = (const float*)d_in[5];
    const float* bdec = (const float*)d_in[6];
    const float* Wmap = (const float*)d_in[7];
    const float* bmap = (const float*)d_in[8];
    float* out = (float*)d_out;
    float* ws  = (float*)d_ws;

    // scratch layout (identical to R5)
    float* partialT = ws;                        // [512][512]
    float *decPart, *mapPart, *cones;
    const size_t fullF = 262144 + 65536 + 16384 + 512;
    if (ws_size >= fullF * sizeof(float)) {
        decPart = ws + 262144;
        mapPart = decPart + 65536;
        cones   = mapPart + 16384;
    } else {
        decPart = out;                           // consumed before k_sdf
        mapPart = out + 65536;
        cones   = ws + 262144;                   // read during k_sdf -> ws
    }
    float* out_params = out + (size_t)NQ * KC;

    // capture-safe host-side queries (no stream interaction)
    int dev = 0;  hipGetDevice(&dev);
    int numCU = 0;
    hipDeviceGetAttribute(&numCU, hipDeviceAttributeMultiprocessorCount, dev);
    int maxB = 0;
    hipOccupancyMaxActiveBlocksPerMultiprocessor(&maxB, k_mid, 512, 0);

    bool coop = (numCU > 0) && ((long)maxB * numCU >= 256);
    if (coop) {
        void* args[] = { (void*)&vox, (void*)&Wenc, (void*)&benc, (void*)&Wdec,
                         (void*)&bdec, (void*)&Wmap, (void*)&bmap,
                         (void*)&partialT, (void*)&decPart, (void*)&mapPart,
                         (void*)&out_params, (void*)&cones };
        hipError_t err = hipLaunchCooperativeKernel((const void*)k_mid, dim3(256),
                                                    dim3(512), args, 0, stream);
        if (err != hipSuccess) coop = false;
    }
    if (!coop) {
        k_enc<<<512, 512, 0, stream>>>(vox, Wenc, partialT);
        k_dec<<<128, 512, 0, stream>>>(partialT, benc, Wdec, decPart);
        k_map<<<64, 512, 0, stream>>>(decPart, bdec, Wmap, mapPart);
        k_params<<<1, 256, 0, stream>>>(mapPart, bmap, out_params, cones);
    }
    k_sdf<<<2048, 256, 0, stream>>>(q, cones, out);
}

// Round 9
// 45.395 us; speedup vs baseline: 3.2616x; 3.2616x over previous
//
#include <hip/hip_runtime.h>
#include <math.h>

#define DD 512
#define KC 32
#define NQ 524288
#define EPSF 1e-8f
#define CONE_STRIDE 13

typedef float f4 __attribute__((ext_vector_type(4)));

__device__ __constant__ float c_mult[8]  = {1.f, 1.f, 1.f, 0.01f, 0.03f, 1.7f, 1.7f, 1.7f};
__device__ __constant__ float c_adder[8] = {-0.8f, -0.8f, -0.8f, 0.05f, 0.1f, -1.f, -1.f, -1.f};

// Stage 1: partialT[b][d] = sum over block b's 64 rows of vox[v]*W_enc[v][d].
// [b][d] layout -> the 2KB/block partial store is fully coalesced. Threads
// also prefetch one float4 of W_dec/W_map to warm L3 for k_dec/k_cones.
__global__ __launch_bounds__(512) void k_enc(const float* __restrict__ vox,
                                             const float* __restrict__ Wenc,
                                             const float* __restrict__ Wdec,
                                             const float* __restrict__ Wmap,
                                             float* __restrict__ partialT) {
    __shared__ float4 red4[512];
    const int t = threadIdx.x;
    const int b = blockIdx.x;
    // L3 warm-up for the next kernels (issued first, overlaps main loop)
    f4 pf = {0.f, 0.f, 0.f, 0.f};
    const int idx = b * 512 + t;
    if (idx < 65536 + 32768) {
        pf = (idx < 65536) ? reinterpret_cast<const f4*>(Wdec)[idx]
                           : reinterpret_cast<const f4*>(Wmap)[idx - 65536];
    }
    const int g  = t >> 7;          // row group 0..3
    const int c4 = (t & 127) << 2;  // starting column
    const int v0 = b * 64;
    float4 acc = make_float4(0.f, 0.f, 0.f, 0.f);
    #pragma unroll
    for (int it = 0; it < 16; ++it) {
        const int v = v0 + it * 4 + g;
        const float sv = vox[v];
        const float4 w = *reinterpret_cast<const float4*>(&Wenc[(size_t)v * DD + c4]);
        acc.x += sv * w.x; acc.y += sv * w.y; acc.z += sv * w.z; acc.w += sv * w.w;
    }
    red4[t] = acc;
    __syncthreads();
    const float* red = reinterpret_cast<const float*>(red4);
    const float s = red[t] + red[512 + t] + red[1024 + t] + red[1536 + t];
    partialT[(size_t)b * 512 + t] = s;               // coalesced
    asm volatile("" :: "v"(pf.x), "v"(pf.y));        // keep prefetch alive
}

// Stage 2: decPart[b][d] = sum_{i in block b's 4 rows} relu(feat[i]+b_enc[i]) * W_dec[i][d]
// feat[i] = sum_b partialT[b][i] (partialT is 1MB, L2-hot). Coalesced store.
__global__ __launch_bounds__(512) void k_dec(const float* __restrict__ partialT,
                                             const float* __restrict__ benc,
                                             const float* __restrict__ Wdec,
                                             float* __restrict__ decPart) {
    __shared__ float4 red4[512];
    __shared__ float wsum[8];
    const int t = threadIdx.x;
    const int g = t >> 7;       // row group 0..3
    const int j = t & 127;
    const int i = blockIdx.x * 4 + g;
    float s = 0.f;
    #pragma unroll
    for (int m = 0; m < 4; ++m)
        s += partialT[(size_t)(j + 128 * m) * 512 + i];
    #pragma unroll
    for (int off = 32; off >= 1; off >>= 1) s += __shfl_xor(s, off, 64);
    if ((t & 63) == 0) wsum[t >> 6] = s;
    __syncthreads();
    float fi = wsum[2 * g] + wsum[2 * g + 1] + benc[i];
    fi = fi > 0.f ? fi : 0.f;
    const float4 w = *reinterpret_cast<const float4*>(&Wdec[(size_t)i * DD + (j << 2)]);
    red4[t] = make_float4(fi * w.x, fi * w.y, fi * w.z, fi * w.w);
    __syncthreads();
    const float* red = reinterpret_cast<const float*>(red4);
    const float s2 = red[t] + red[512 + t] + red[1024 + t] + red[1536 + t];
    decPart[(size_t)blockIdx.x * 512 + t] = s2;   // coalesced
}

// Stage 3 (merged MAP+PARAMS, no cross-block dependency): 256 blocks.
// Blocks 0..7: each redundantly reduces decPart (256KB, coalesced, L2-hot)
// to the full dec vector, computes its 32 map columns (j = 32b..32b+31) over
// ALL 512 dec rows (16 chunks x 32 rows — R8 bug was 16x16=256 rows),
// sigmoid*mult+adder -> 32 output params + derives its 4 cones into ws.
// Blocks 8..255: prefetch q (6MB) into L3 for k_sdf.
__global__ __launch_bounds__(512) void k_cones(const float* __restrict__ decPart,
                                               const float* __restrict__ bdec,
                                               const float* __restrict__ Wmap,
                                               const float* __restrict__ bmap,
                                               const float* __restrict__ q,
                                               float* __restrict__ out_params,
                                               float* __restrict__ cones,
                                               float* __restrict__ qsink) {
    const int t = threadIdx.x;
    const int b = blockIdx.x;
    if (b >= 8) {
        // ---- q prefetch: grid-stride float4 reads, keep via sink ----
        const f4* q4 = reinterpret_cast<const f4*>(q);
        f4 acc = {0.f, 0.f, 0.f, 0.f};
        const int nth = 248 * 512;
        for (int i = (b - 8) * 512 + t; i < (NQ * 3) / 4; i += nth) {
            f4 v = q4[i];
            acc.x += v.x; acc.y += v.y; acc.z += v.z; acc.w += v.w;
        }
        if (t == 0) qsink[b] = acc.x + acc.y + acc.z + acc.w;
        return;
    }
    __shared__ f4 red[512];
    __shared__ float dec_lds[DD];
    __shared__ float psum[512];
    __shared__ float pbuf[32];
    // ---- dec = relu(colsum(decPart) + b_dec): float4 coalesced ----
    {
        const f4* dP4 = reinterpret_cast<const f4*>(decPart);
        const int d4 = t & 127;          // float4 index: d = 4*d4..4*d4+3
        const int bc = t >> 7;           // b-chunk 0..3
        f4 a = {0.f, 0.f, 0.f, 0.f};
        #pragma unroll
        for (int m = 0; m < 32; ++m) {
            const f4 v = dP4[(size_t)(bc * 32 + m) * 128 + d4];
            a.x += v.x; a.y += v.y; a.z += v.z; a.w += v.w;
        }
        red[t] = a;
        __syncthreads();
        if (t < 128) {
            f4 s = red[t];
            const f4 s1 = red[t + 128], s2 = red[t + 256], s3 = red[t + 384];
            s.x += s1.x + s2.x + s3.x; s.y += s1.y + s2.y + s3.y;
            s.z += s1.z + s2.z + s3.z; s.w += s1.w + s2.w + s3.w;
            const f4 bd = reinterpret_cast<const f4*>(bdec)[t];
            dec_lds[4*t+0] = fmaxf(s.x + bd.x, 0.f);
            dec_lds[4*t+1] = fmaxf(s.y + bd.y, 0.f);
            dec_lds[4*t+2] = fmaxf(s.z + bd.z, 0.f);
            dec_lds[4*t+3] = fmaxf(s.w + bd.w, 0.f);
        }
        __syncthreads();
    }
    // ---- map columns j = 32b + (t&31): 16 chunks x 32 rows = ALL 512 ----
    {
        const int jj = t & 31;
        const int c  = t >> 5;           // chunk 0..15
        const int j  = b * 32 + jj;
        float acc = 0.f;
        #pragma unroll
        for (int r = 0; r < 32; ++r) {
            const int i = c * 32 + r;    // covers 0..511
            acc += dec_lds[i] * Wmap[(size_t)i * 256 + j];
        }
        psum[c * 32 + jj] = acc;
        __syncthreads();
        if (t < 32) {
            float m = 0.f;
            #pragma unroll
            for (int cc = 0; cc < 16; ++cc) m += psum[cc * 32 + t];
            const float tot = m + bmap[b * 32 + t];
            const float sig = 1.f / (1.f + expf(-tot));
            const float val = sig * c_mult[t & 7] + c_adder[t & 7];
            out_params[b * 32 + t] = val;
            pbuf[t] = val;
        }
        __syncthreads();
    }
    // ---- derive 4 cones ----
    if (t < 4) {
        const float* p = &pbuf[t * 8];
        const float cx = p[0], cy = p[1], cz = p[2];
        const float r  = p[3], hh = p[4];
        const float ox = p[5], oy = p[6], oz = p[7];
        const float nrm = sqrtf(ox*ox + oy*oy + oz*oz) + EPSF;
        const float inv = 1.f / nrm;
        const float inv_h = 1.f / (hh + EPSF);
        float* ck = &cones[(b * 4 + t) * CONE_STRIDE];
        ck[0] = cx;        ck[1] = cy;       ck[2] = cz;
        ck[3] = ox * inv;  ck[4] = oy * inv; ck[5] = oz * inv;
        ck[6] = r;         ck[7] = hh;       ck[8] = inv_h;
        ck[9] = r * inv_h; ck[10] = 0.f;     ck[11] = 0.f;  ck[12] = 0.f;
    }
}

// Stage 4: SDF eval — fat blocks, cones in registers, coalesced NT stores.
__global__ __launch_bounds__(256) void k_sdf(const float* __restrict__ q,
                                             const float* __restrict__ cones,
                                             float* __restrict__ out) {
    __shared__ float c[KC * CONE_STRIDE];
    const int t = threadIdx.x;
    c[t] = cones[t];
    if (t < KC * CONE_STRIDE - 256) c[256 + t] = cones[256 + t];
    __syncthreads();
    const int k0 = (t & 7) << 2;
    float cx[4], cy[4], cz[4], ax[4], ay[4], az[4], cr[4], chh[4], rih[4];
    #pragma unroll
    for (int kk = 0; kk < 4; ++kk) {
        const float* ck = &c[(k0 + kk) * CONE_STRIDE];
        cx[kk] = ck[0]; cy[kk] = ck[1]; cz[kk] = ck[2];
        ax[kk] = ck[3]; ay[kk] = ck[4]; az[kk] = ck[5];
        cr[kk] = ck[6]; chh[kk] = ck[7]; rih[kk] = ck[9];
    }
    const size_t qbase = (size_t)blockIdx.x * 256;
    const int nl = t >> 3;
    #pragma unroll
    for (int tile = 0; tile < 8; ++tile) {
        const size_t n = qbase + tile * 32 + nl;
        const float qx = q[n * 3 + 0];
        const float qy = q[n * 3 + 1];
        const float qz = q[n * 3 + 2];
        f4 o;
        #pragma unroll
        for (int kk = 0; kk < 4; ++kk) {
            const float vx = qx - cx[kk];
            const float vy = qy - cy[kk];
            const float vz = qz - cz[kk];
            const float proj = vx*ax[kk] + vy*ay[kk] + vz*az[kk];
            const float d2 = vx*vx + vy*vy + vz*vz;
            float pp = d2 - proj * proj;
            pp = pp > 0.f ? pp : 0.f;
            const float perp = sqrtf(pp);
            const float slant = perp - cr[kk] + rih[kk] * proj;
            const float cap = fabsf(proj) - chh[kk];
            o[kk] = slant > cap ? slant : cap;
        }
        __builtin_nontemporal_store(o, reinterpret_cast<f4*>(&out[n * (size_t)KC + k0]));
    }
}

extern "C" void kernel_launch(void* const* d_in, const int* in_sizes, int n_in,
                              void* d_out, int out_size, void* d_ws, size_t ws_size,
                              hipStream_t stream) {
    const float* vox  = (const float*)d_in[0];
    const float* q    = (const float*)d_in[1];
    // d_in[2] = initial_centers: unused by the reference
    const float* Wenc = (const float*)d_in[3];
    const float* benc = (const float*)d_in[4];
    const float* Wdec = (const float*)d_in[5];
    const float* bdec = (const float*)d_in[6];
    const float* Wmap = (const float*)d_in[7];
    const float* bmap = (const float*)d_in[8];
    float* out = (float*)d_out;
    float* ws  = (float*)d_ws;

    float* partialT = ws;                        // [512][512], always ws
    float *decPart, *cones, *qsink;
    const size_t fullF = 262144 + 65536 + 512 + 256;
    if (ws_size >= fullF * sizeof(float)) {
        decPart = ws + 262144;                   // [128][512]
        cones   = decPart + 65536;               // 416 floats
        qsink   = cones + 512;                   // 256 floats
    } else {
        // spill decPart to d_out's front: consumed by k_cones strictly
        // before k_sdf overwrites it (stream order).
        decPart = out;                           // [128][512]
        cones   = ws + 262144;                   // read DURING k_sdf -> ws
        qsink   = cones + 512;
    }
    float* out_params = out + (size_t)NQ * KC;

    k_enc<<<512, 512, 0, stream>>>(vox, Wenc, Wdec, Wmap, partialT);
    k_dec<<<128, 512, 0, stream>>>(partialT, benc, Wdec, decPart);
    k_cones<<<256, 512, 0, stream>>>(decPart, bdec, Wmap, bmap, q,
                                     out_params, cones, qsink);
    k_sdf<<<2048, 256, 0, stream>>>(q, cones, out);
}